// Round 1
// baseline (1552.045 us; speedup 1.0000x reference)
//
#include <hip/hip_runtime.h>

namespace {

constexpr int NATOM = 32;
constexpr int T = 465;       // (N-1)(N-2)/2
constexpr int M = 31;        // others count
constexpr int NB = 4;        // batch blocks per center (covers n<=256; last loops)
constexpr float FCUT = 3.5f;
constexpr float PI_OVER_CUT = 0.8975979010256552f; // pi/3.5

__device__ __forceinline__ float ftanh(float x) {
    // tanh(x) = (e^{2x}-1)/(e^{2x}+1), clamped so e stays finite
    x = fminf(fmaxf(x, -15.0f), 15.0f);
    const float e = __expf(2.0f * x);
    return (e - 1.0f) * __builtin_amdgcn_rcpf(e + 1.0f);
}

// 64->64 layer: xr (regs) -> tanh -> bufO[feat][lane]
#define LAYER64(Wp, Bp)                                                        \
    _Pragma("clang loop unroll(disable)")                                      \
    for (int oc = 0; oc < 8; ++oc) {                                           \
        float acc[8];                                                          \
        _Pragma("unroll")                                                      \
        for (int u = 0; u < 8; ++u) acc[u] = Bp[oc * 8 + u];                   \
        _Pragma("unroll")                                                      \
        for (int kk = 0; kk < 64; ++kk) {                                      \
            const float xv = xr[kk];                                           \
            _Pragma("unroll")                                                  \
            for (int u = 0; u < 8; ++u)                                        \
                acc[u] += xv * Wp[kk * 64 + oc * 8 + u];                       \
        }                                                                      \
        _Pragma("unroll")                                                      \
        for (int u = 0; u < 8; ++u)                                            \
            bufO[(oc * 8 + u) * 64 + lane] = ftanh(acc[u]);                    \
    }                                                                          \
    __syncthreads();

__global__ __launch_bounds__(64, 1)
void aev_kernel(const float* __restrict__ D, const float* __restrict__ Z,
                const float* __restrict__ W0, const float* __restrict__ B0,
                const float* __restrict__ W1, const float* __restrict__ B1,
                const float* __restrict__ W2, const float* __restrict__ B2,
                const float* __restrict__ W3, const float* __restrict__ B3,
                const float* __restrict__ W4, const float* __restrict__ B4,
                const float* __restrict__ W5, const float* __restrict__ B5,
                const float* __restrict__ W6, const float* __restrict__ B6,
                float* __restrict__ out)
{
    __shared__ float bufO[64 * 64];   // current layer output, [feat][lane]
    __shared__ float bufR[64 * 64];   // residual (blk1); reused as L6 reduce scratch
    __shared__ float comp[64 * 10];   // compacted window: 9 features + smooth
    __shared__ float aev[256];        // per-center accumulator

    const int lane   = threadIdx.x;
    const int center = blockIdx.x;
    const int batch  = blockIdx.y;
    const int bi = center >> 5;
    const int i  = center & 31;

    const float* __restrict__ Drow = D + bi * NATOM * NATOM;
    const float* __restrict__ Zrow = Z + bi * NATOM;

    #pragma unroll
    for (int c = 0; c < 4; ++c) aev[c * 64 + lane] = 0.0f;

    const float z_i = Zrow[i];

    int winLo = batch * 64;
    bool wrote = false;
    int ntot = 0;

    for (;;) {
        // ---------- phase A: scan all triplets, compact [winLo, winLo+64) ----------
        #pragma unroll
        for (int q = 0; q < 10; ++q) comp[lane * 10 + q] = 0.0f;
        __syncthreads();

        int base = 0;
        for (int t0 = 0; t0 < T; t0 += 64) {
            const int t = t0 + lane;
            bool act = false;
            float rij = 0.f, rik = 0.f;
            int j = 0, k = 0;
            if (t < T) {
                // unrank t -> pair (a,b), 0<=a<b<31, over "others" list
                int a = 0, rem = t;
                while (rem >= M - 1 - a) { rem -= M - 1 - a; ++a; }
                const int b = a + 1 + rem;
                j = a + (a >= i);
                k = b + (b >= i);
                rij = Drow[i * NATOM + j];
                rik = Drow[i * NATOM + k];
                act = (rij < FCUT) && (rik < FCUT);
            }
            const unsigned long long mb = __ballot(act);
            const int slot = base + __popcll(mb & ((1ull << lane) - 1ull));
            base += (int)__popcll(mb);
            if (act && slot >= winLo && slot < winLo + 64) {
                const int idx = slot - winLo;
                const float rjk = Drow[j * NATOM + k];
                const float zj = Zrow[j], zk = Zrow[k];
                const float rij2 = rij * rij, rik2 = rik * rik, rjk2 = rjk * rjk;
                const float ci = (rij2 + rik2 - rjk2) / fmaxf(2.f * rij * rik, 1e-10f);
                const float cj = (rij2 + rjk2 - rik2) / fmaxf(2.f * rij * rjk, 1e-10f);
                const float ck = (rik2 + rjk2 - rij2) / fmaxf(2.f * rik * rjk, 1e-10f);
                const float g0 = rij + rik + rjk;
                const float g1 = rij * rik + rij * rjk + rik * rjk;
                const float g2 = rij * rik * rjk;
                const float gn = sqrtf(g0 * g0 + g1 * g1 + g2 * g2) + 1e-7f;
                const float s0 = z_i + zj + zk;
                const float s1 = ci + cj + ck;
                const float s2 = z_i * (zj + zk) + zj * zk - ci * (cj + ck) - cj * ck;
                const float s3 = z_i * (cj + ck) + ci * (zj + zk) + zj * ck + cj * zk;
                const float s4 = z_i * (zj * zk - cj * ck) - ci * (zj * ck + cj * zk);
                const float s5 = z_i * (zj * ck + cj * zk) + ci * (zj * zk - cj * ck);
                const float sn = sqrtf(s0*s0 + s1*s1 + s2*s2 + s3*s3 + s4*s4 + s5*s5) + 1e-7f;
                const float fij = 0.5f * cosf(PI_OVER_CUT * rij) + 0.5f;
                const float fik = 0.5f * cosf(PI_OVER_CUT * rik) + 0.5f;
                const float rg = 1.0f / gn, rs = 1.0f / sn;
                comp[idx * 10 + 0] = g0 * rg;
                comp[idx * 10 + 1] = g1 * rg;
                comp[idx * 10 + 2] = g2 * rg;
                comp[idx * 10 + 3] = s0 * rs;
                comp[idx * 10 + 4] = s1 * rs;
                comp[idx * 10 + 5] = s2 * rs;
                comp[idx * 10 + 6] = s3 * rs;
                comp[idx * 10 + 7] = s4 * rs;
                comp[idx * 10 + 8] = s5 * rs;
                comp[idx * 10 + 9] = fij * fik;
            }
        }
        __syncthreads();
        ntot = base;
        const int rows = min(max(ntot - winLo, 0), 64);

        // ---------- phase B: MLP for this window, row-per-lane ----------
        if (rows > 0) {
            wrote = true;
            float x[9];
            #pragma unroll
            for (int q = 0; q < 9; ++q) x[q] = comp[lane * 10 + q];
            const float sm = comp[lane * 10 + 9];   // 0 for lanes >= rows

            float xr[64];
            // L0: 9 -> 64
            _Pragma("clang loop unroll(disable)")
            for (int oc = 0; oc < 8; ++oc) {
                float acc[8];
                #pragma unroll
                for (int u = 0; u < 8; ++u) acc[u] = B0[oc * 8 + u];
                #pragma unroll
                for (int kk = 0; kk < 9; ++kk) {
                    const float xv = x[kk];
                    #pragma unroll
                    for (int u = 0; u < 8; ++u)
                        acc[u] += xv * W0[kk * 64 + oc * 8 + u];
                }
                #pragma unroll
                for (int u = 0; u < 8; ++u)
                    bufO[(oc * 8 + u) * 64 + lane] = ftanh(acc[u]);
            }
            __syncthreads();
            #pragma unroll
            for (int f = 0; f < 64; ++f) xr[f] = bufO[f * 64 + lane]; // x_res

            // L1, then blk1 = h + x_res (keep in regs + bufR)
            LAYER64(W1, B1)
            #pragma unroll
            for (int f = 0; f < 64; ++f) {
                const float v = xr[f] + bufO[f * 64 + lane];
                xr[f] = v;
                bufR[f * 64 + lane] = v;
            }
            __syncthreads();

            // L2, L3
            LAYER64(W2, B2)
            #pragma unroll
            for (int f = 0; f < 64; ++f) xr[f] = bufO[f * 64 + lane];
            LAYER64(W3, B3)
            #pragma unroll
            for (int f = 0; f < 64; ++f) xr[f] = bufO[f * 64 + lane];

            // L4, then blk2 = h + blk1
            LAYER64(W4, B4)
            #pragma unroll
            for (int f = 0; f < 64; ++f)
                xr[f] = bufO[f * 64 + lane] + bufR[f * 64 + lane];
            __syncthreads();

            // L5: 64 -> 128 (two halves through 64-wide bufO)
            float xt[128];
            _Pragma("clang loop unroll(disable)")
            for (int oc = 0; oc < 8; ++oc) {
                float acc[8];
                #pragma unroll
                for (int u = 0; u < 8; ++u) acc[u] = B5[oc * 8 + u];
                #pragma unroll
                for (int kk = 0; kk < 64; ++kk) {
                    const float xv = xr[kk];
                    #pragma unroll
                    for (int u = 0; u < 8; ++u)
                        acc[u] += xv * W5[kk * 128 + oc * 8 + u];
                }
                #pragma unroll
                for (int u = 0; u < 8; ++u)
                    bufO[(oc * 8 + u) * 64 + lane] = ftanh(acc[u]);
            }
            __syncthreads();
            #pragma unroll
            for (int f = 0; f < 64; ++f) xt[f] = bufO[f * 64 + lane];
            _Pragma("clang loop unroll(disable)")
            for (int oc = 8; oc < 16; ++oc) {
                float acc[8];
                #pragma unroll
                for (int u = 0; u < 8; ++u) acc[u] = B5[oc * 8 + u];
                #pragma unroll
                for (int kk = 0; kk < 64; ++kk) {
                    const float xv = xr[kk];
                    #pragma unroll
                    for (int u = 0; u < 8; ++u)
                        acc[u] += xv * W5[kk * 128 + oc * 8 + u];
                }
                #pragma unroll
                for (int u = 0; u < 8; ++u)
                    bufO[((oc - 8) * 8 + u) * 64 + lane] = ftanh(acc[u]);
            }
            __syncthreads();
            #pragma unroll
            for (int f = 0; f < 64; ++f) xt[64 + f] = bufO[f * 64 + lane];

            // L6: 128 -> 256, chunked; reduce over lanes (rows) into aev
            _Pragma("clang loop unroll(disable)")
            for (int oc = 0; oc < 32; ++oc) {
                float acc[8];
                #pragma unroll
                for (int u = 0; u < 8; ++u) acc[u] = B6[oc * 8 + u];
                #pragma unroll
                for (int kk = 0; kk < 128; ++kk) {
                    const float xv = xt[kk];
                    #pragma unroll
                    for (int u = 0; u < 8; ++u)
                        acc[u] += xv * W6[kk * 256 + oc * 8 + u];
                }
                #pragma unroll
                for (int u = 0; u < 8; ++u)
                    bufR[u * 64 + lane] = ftanh(acc[u]) * sm;
                __syncthreads();
                const int uo = lane & 7, seg = lane >> 3;
                float p = 0.f;
                #pragma unroll
                for (int q = 0; q < 8; ++q)
                    p += bufR[uo * 64 + seg * 8 + q];
                atomicAdd(&aev[oc * 8 + uo], p);
                __syncthreads();
            }
        }

        if (batch < NB - 1) break;   // batches 0..2: exactly one window
        winLo += 64;                 // last batch: loop remaining windows (rare)
        if (winLo >= ntot) break;
    }

    if (wrote) {
        __syncthreads();
        #pragma unroll
        for (int c = 0; c < 4; ++c)
            atomicAdd(&out[center * 256 + c * 64 + lane], aev[c * 64 + lane]);
    }
}

} // namespace

extern "C" void kernel_launch(void* const* d_in, const int* in_sizes, int n_in,
                              void* d_out, int out_size, void* d_ws, size_t ws_size,
                              hipStream_t stream) {
    (void)in_sizes; (void)n_in; (void)d_ws; (void)ws_size;

    const float* D  = (const float*)d_in[0];
    const float* Z  = (const float*)d_in[1];
    const float* W0 = (const float*)d_in[2];  const float* B0 = (const float*)d_in[3];
    const float* W1 = (const float*)d_in[4];  const float* B1 = (const float*)d_in[5];
    const float* W2 = (const float*)d_in[6];  const float* B2 = (const float*)d_in[7];
    const float* W3 = (const float*)d_in[8];  const float* B3 = (const float*)d_in[9];
    const float* W4 = (const float*)d_in[10]; const float* B4 = (const float*)d_in[11];
    const float* W5 = (const float*)d_in[12]; const float* B5 = (const float*)d_in[13];
    const float* W6 = (const float*)d_in[14]; const float* B6 = (const float*)d_in[15];
    float* out = (float*)d_out;

    hipMemsetAsync(d_out, 0, sizeof(float) * (size_t)out_size, stream);

    dim3 grid(32 * 32, NB);
    aev_kernel<<<grid, 64, 0, stream>>>(D, Z, W0, B0, W1, B1, W2, B2,
                                        W3, B3, W4, B4, W5, B5, W6, B6, out);
}

// Round 2
// 1355.488 us; speedup vs baseline: 1.1450x; 1.1450x over previous
//
#include <hip/hip_runtime.h>

namespace {

constexpr int T = 465;        // (N-1)(N-2)/2 triplets per center
constexpr int M = 31;         // "others" count
constexpr float FCUT = 3.5f;
constexpr float PI_OVER_CUT = 0.8975979010256552f; // pi/3.5
constexpr int REC = 12;       // floats per compacted row record
constexpr int K2_BLOCKS = 2048;
constexpr int MAXROWS_HARD = 1024 * 480; // worst case, padded

__device__ __forceinline__ float ftanh(float x) {
    x = fminf(fmaxf(x, -15.0f), 15.0f);
    const float e = __expf(2.0f * x);
    return (e - 1.0f) * __builtin_amdgcn_rcpf(e + 1.0f);
}

// ---------------- K1: compact active triplets into global row list ----------
__global__ __launch_bounds__(64, 1)
void feat_kernel(const float* __restrict__ D, const float* __restrict__ Z,
                 float* __restrict__ rows, int* __restrict__ ctr, int maxrows)
{
    const int lane = threadIdx.x;
    const int center = blockIdx.x;
    const int bi = center >> 5, i = center & 31;
    const float* __restrict__ Drow = D + bi * 1024;
    const float* __restrict__ Zrow = Z + bi * 32;
    const float z_i = Zrow[i];

    // pass 1: activity masks + count
    unsigned long long masks[8];
    int cnt = 0;
    #pragma unroll
    for (int rnd = 0; rnd < 8; ++rnd) {
        const int t = rnd * 64 + lane;
        bool act = false;
        if (t < T) {
            int a = 0, rem = t;
            while (rem >= M - 1 - a) { rem -= M - 1 - a; ++a; }
            const int b = a + 1 + rem;
            const int j = a + (a >= i);
            const int k = b + (b >= i);
            const float rij = Drow[i * 32 + j];
            const float rik = Drow[i * 32 + k];
            act = (rij < FCUT) && (rik < FCUT);
        }
        masks[rnd] = __ballot(act);
        cnt += (int)__popcll(masks[rnd]);
    }
    const int padded = (cnt + 15) & ~15;   // 16-alignment: every 16-seg is one center
    if (padded == 0) return;
    int base = 0;
    if (lane == 0) base = atomicAdd(ctr, padded);
    base = __shfl(base, 0);
    if (base + padded > maxrows) return;   // defensive; won't trigger at real density

    // pass 2: recompute + write active rows
    int pre = 0;
    #pragma unroll
    for (int rnd = 0; rnd < 8; ++rnd) {
        const unsigned long long mb = masks[rnd];
        const bool act = (mb >> lane) & 1ull;
        const int slot = base + pre + (int)__popcll(mb & ((1ull << lane) - 1ull));
        pre += (int)__popcll(mb);
        if (act) {
            const int t = rnd * 64 + lane;
            int a = 0, rem = t;
            while (rem >= M - 1 - a) { rem -= M - 1 - a; ++a; }
            const int b = a + 1 + rem;
            const int j = a + (a >= i);
            const int k = b + (b >= i);
            const float rij = Drow[i * 32 + j];
            const float rik = Drow[i * 32 + k];
            const float rjk = Drow[j * 32 + k];
            const float zj = Zrow[j], zk = Zrow[k];
            const float rij2 = rij * rij, rik2 = rik * rik, rjk2 = rjk * rjk;
            const float ci = (rij2 + rik2 - rjk2) / fmaxf(2.f * rij * rik, 1e-10f);
            const float cj = (rij2 + rjk2 - rik2) / fmaxf(2.f * rij * rjk, 1e-10f);
            const float ck = (rik2 + rjk2 - rij2) / fmaxf(2.f * rik * rjk, 1e-10f);
            const float g0 = rij + rik + rjk;
            const float g1 = rij * rik + rij * rjk + rik * rjk;
            const float g2 = rij * rik * rjk;
            const float rg = 1.0f / (sqrtf(g0 * g0 + g1 * g1 + g2 * g2) + 1e-7f);
            const float s0 = z_i + zj + zk;
            const float s1 = ci + cj + ck;
            const float s2 = z_i * (zj + zk) + zj * zk - ci * (cj + ck) - cj * ck;
            const float s3 = z_i * (cj + ck) + ci * (zj + zk) + zj * ck + cj * zk;
            const float s4 = z_i * (zj * zk - cj * ck) - ci * (zj * ck + cj * zk);
            const float s5 = z_i * (zj * ck + cj * zk) + ci * (zj * zk - cj * ck);
            const float rs = 1.0f / (sqrtf(s0*s0 + s1*s1 + s2*s2 + s3*s3 + s4*s4 + s5*s5) + 1e-7f);
            const float fij = 0.5f * cosf(PI_OVER_CUT * rij) + 0.5f;
            const float fik = 0.5f * cosf(PI_OVER_CUT * rik) + 0.5f;
            float4* dst = (float4*)(rows + (size_t)slot * REC);
            dst[0] = make_float4(g0 * rg, g1 * rg, g2 * rg, s0 * rs);
            dst[1] = make_float4(s1 * rs, s2 * rs, s3 * rs, s4 * rs);
            dst[2] = make_float4(s5 * rs, fij * fik, __int_as_float(center), 0.f);
        }
    }
    // padding rows (sm = 0 -> contribute nothing); tail segment always starts real
    for (int p = cnt + lane; p < padded; p += 64) {
        float4* dst = (float4*)(rows + (size_t)(base + p) * REC);
        dst[0] = make_float4(0.f, 0.f, 0.f, 0.f);
        dst[1] = make_float4(0.f, 0.f, 0.f, 0.f);
        dst[2] = make_float4(0.f, 0.f, __int_as_float(center), 0.f);
    }
}

// ---------------- K2: MLP over compacted rows -------------------------------
// 1 wave/block, no __syncthreads. Inputs in LDS column [feat][lane];
// output accumulators in registers (compile-time indices only).
__global__ __launch_bounds__(64, 2)
void mlp_kernel(const float* __restrict__ rows, const int* __restrict__ ctr,
                const float* __restrict__ W0, const float* __restrict__ B0,
                const float* __restrict__ W1, const float* __restrict__ B1,
                const float* __restrict__ W2, const float* __restrict__ B2,
                const float* __restrict__ W3, const float* __restrict__ B3,
                const float* __restrict__ W4, const float* __restrict__ B4,
                const float* __restrict__ W5, const float* __restrict__ B5,
                const float* __restrict__ W6, const float* __restrict__ B6,
                float* __restrict__ out)
{
    __shared__ float buf[128 * 64];  // [feat][lane], 32 KB
    const int lane = threadIdx.x;
    const int nrows = *ctr;          // multiple of 16

    for (int r0 = blockIdx.x * 64; r0 < nrows; r0 += K2_BLOCKS * 64) {
        const int r = r0 + lane;
        const bool valid = r < nrows;
        float sm = 0.f;
        int centr = -1;
        {
            float4 v0 = make_float4(0,0,0,0), v1 = v0, v2 = v0;
            if (valid) {
                const float4* rec = (const float4*)(rows + (size_t)r * REC);
                v0 = rec[0]; v1 = rec[1]; v2 = rec[2];
                sm = v2.y;
                centr = __float_as_int(v2.z);
            }
            buf[0*64+lane]=v0.x; buf[1*64+lane]=v0.y; buf[2*64+lane]=v0.z;
            buf[3*64+lane]=v0.w; buf[4*64+lane]=v1.x; buf[5*64+lane]=v1.y;
            buf[6*64+lane]=v1.z; buf[7*64+lane]=v1.w; buf[8*64+lane]=v2.x;
        }

        float acc[64], res[64];

        // L0: 9 -> 64 ; res = x_res
        #pragma unroll
        for (int u = 0; u < 64; ++u) acc[u] = B0[u];
        #pragma unroll 3
        for (int kk = 0; kk < 9; ++kk) {
            const float xv = buf[kk * 64 + lane];
            const float* __restrict__ w = W0 + kk * 64;
            #pragma unroll
            for (int u = 0; u < 64; ++u) acc[u] = fmaf(xv, w[u], acc[u]);
        }
        #pragma unroll
        for (int u = 0; u < 64; ++u) { res[u] = ftanh(acc[u]); buf[u * 64 + lane] = res[u]; }

        // L1 ; res = blk1 = h + x_res
        #pragma unroll
        for (int u = 0; u < 64; ++u) acc[u] = B1[u];
        #pragma unroll 2
        for (int kk = 0; kk < 64; ++kk) {
            const float xv = buf[kk * 64 + lane];
            const float* __restrict__ w = W1 + kk * 64;
            #pragma unroll
            for (int u = 0; u < 64; ++u) acc[u] = fmaf(xv, w[u], acc[u]);
        }
        #pragma unroll
        for (int u = 0; u < 64; ++u) { res[u] += ftanh(acc[u]); buf[u * 64 + lane] = res[u]; }

        // L2
        #pragma unroll
        for (int u = 0; u < 64; ++u) acc[u] = B2[u];
        #pragma unroll 2
        for (int kk = 0; kk < 64; ++kk) {
            const float xv = buf[kk * 64 + lane];
            const float* __restrict__ w = W2 + kk * 64;
            #pragma unroll
            for (int u = 0; u < 64; ++u) acc[u] = fmaf(xv, w[u], acc[u]);
        }
        #pragma unroll
        for (int u = 0; u < 64; ++u) buf[u * 64 + lane] = ftanh(acc[u]);

        // L3
        #pragma unroll
        for (int u = 0; u < 64; ++u) acc[u] = B3[u];
        #pragma unroll 2
        for (int kk = 0; kk < 64; ++kk) {
            const float xv = buf[kk * 64 + lane];
            const float* __restrict__ w = W3 + kk * 64;
            #pragma unroll
            for (int u = 0; u < 64; ++u) acc[u] = fmaf(xv, w[u], acc[u]);
        }
        #pragma unroll
        for (int u = 0; u < 64; ++u) buf[u * 64 + lane] = ftanh(acc[u]);

        // L4 ; res = blk2 = h + blk1
        #pragma unroll
        for (int u = 0; u < 64; ++u) acc[u] = B4[u];
        #pragma unroll 2
        for (int kk = 0; kk < 64; ++kk) {
            const float xv = buf[kk * 64 + lane];
            const float* __restrict__ w = W4 + kk * 64;
            #pragma unroll
            for (int u = 0; u < 64; ++u) acc[u] = fmaf(xv, w[u], acc[u]);
        }
        #pragma unroll
        for (int u = 0; u < 64; ++u) { res[u] += ftanh(acc[u]); buf[u * 64 + lane] = res[u]; }

        // L5: 64 -> 128 (res dead afterwards)
        {
            float a5[128];
            #pragma unroll
            for (int u = 0; u < 128; ++u) a5[u] = B5[u];
            #pragma unroll 2
            for (int kk = 0; kk < 64; ++kk) {
                const float xv = buf[kk * 64 + lane];
                const float* __restrict__ w = W5 + kk * 128;
                #pragma unroll
                for (int u = 0; u < 128; ++u) a5[u] = fmaf(xv, w[u], a5[u]);
            }
            #pragma unroll
            for (int u = 0; u < 128; ++u) buf[u * 64 + lane] = ftanh(a5[u]);
        }

        // L6: 128 -> 256 in 4 output groups; segmented (16-lane) reduce + atomics
        #pragma unroll 1
        for (int g = 0; g < 4; ++g) {
            float a6[64];
            #pragma unroll
            for (int u = 0; u < 64; ++u) a6[u] = B6[g * 64 + u];
            #pragma unroll 2
            for (int kk = 0; kk < 128; ++kk) {
                const float xv = buf[kk * 64 + lane];
                const float* __restrict__ w = W6 + kk * 256 + g * 64;
                #pragma unroll
                for (int u = 0; u < 64; ++u) a6[u] = fmaf(xv, w[u], a6[u]);
            }
            #pragma unroll
            for (int u = 0; u < 64; ++u) {
                float v = ftanh(a6[u]) * sm;
                v += __shfl_xor(v, 1);
                v += __shfl_xor(v, 2);
                v += __shfl_xor(v, 4);
                v += __shfl_xor(v, 8);
                a6[u] = v;   // segment sum, same in all 16 lanes
            }
            if (((lane & 15) == 0) && centr >= 0) {
                float* __restrict__ op = out + (size_t)centr * 256 + g * 64;
                #pragma unroll
                for (int u = 0; u < 64; ++u) atomicAdd(op + u, a6[u]);
            }
        }
    }
}

} // namespace

extern "C" void kernel_launch(void* const* d_in, const int* in_sizes, int n_in,
                              void* d_out, int out_size, void* d_ws, size_t ws_size,
                              hipStream_t stream) {
    (void)in_sizes; (void)n_in;

    const float* D  = (const float*)d_in[0];
    const float* Z  = (const float*)d_in[1];
    const float* W0 = (const float*)d_in[2];  const float* B0 = (const float*)d_in[3];
    const float* W1 = (const float*)d_in[4];  const float* B1 = (const float*)d_in[5];
    const float* W2 = (const float*)d_in[6];  const float* B2 = (const float*)d_in[7];
    const float* W3 = (const float*)d_in[8];  const float* B3 = (const float*)d_in[9];
    const float* W4 = (const float*)d_in[10]; const float* B4 = (const float*)d_in[11];
    const float* W5 = (const float*)d_in[12]; const float* B5 = (const float*)d_in[13];
    const float* W6 = (const float*)d_in[14]; const float* B6 = (const float*)d_in[15];
    float* out = (float*)d_out;

    int* ctr = (int*)d_ws;
    float* rowbuf = (float*)((char*)d_ws + 64);
    size_t avail = (ws_size > 64) ? (ws_size - 64) / (REC * sizeof(float)) : 0;
    int maxrows = (int)((avail < (size_t)MAXROWS_HARD) ? avail : (size_t)MAXROWS_HARD);

    hipMemsetAsync(d_ws, 0, 64, stream);
    hipMemsetAsync(d_out, 0, sizeof(float) * (size_t)out_size, stream);

    feat_kernel<<<1024, 64, 0, stream>>>(D, Z, rowbuf, ctr, maxrows);
    mlp_kernel<<<K2_BLOCKS, 64, 0, stream>>>(rowbuf, ctr,
                                             W0, B0, W1, B1, W2, B2, W3, B3,
                                             W4, B4, W5, B5, W6, B6, out);
}